// Round 3
// baseline (840.895 us; speedup 1.0000x reference)
//
#include <hip/hip_runtime.h>
#include <cstdint>

// SREChead: stem 1x1 (128->64) + 2x 3x3 (64->64), each BN+SiLU, then 1x1
// reg(4)/obj(1) heads + YOLOX decode. B=64, 80x80, stride 32.
// R2: all operands staged through LDS (XOR-swizzled, bank-uniform); conv
// weights register-resident via wave co-split; unpadded NHWC bf16 in ws.

typedef short short8 __attribute__((ext_vector_type(8)));
typedef float floatx4 __attribute__((ext_vector_type(4)));
typedef float fx4 __attribute__((ext_vector_type(4)));
typedef unsigned short us4 __attribute__((ext_vector_type(4)));

#define NPIX 6400

static __device__ __forceinline__ unsigned short f2bf(float f) {
    unsigned u = __builtin_bit_cast(unsigned, f);
    u += 0x7fffu + ((u >> 16) & 1u);      // round-to-nearest-even
    return (unsigned short)(u >> 16);
}

static __device__ __forceinline__ float silu_(float v) {
    return v / (1.0f + __expf(-v));
}

// ---------------------------------------------------------------------------
// Rearrange 3x3 weights [64co][64ci][3][3] fp32 -> bf16 MFMA A-frag order:
// wB[kb(18)][ct(4)][lane(64)][j(8)], co = ct*16+(lane&15),
// k = kb*32+(lane>>4)*8+j, ci = k&63, tap = k>>6 (= dy*3+dx).
__global__ __launch_bounds__(256) void rearr_w_kernel(
    const float* __restrict__ w1, const float* __restrict__ w2,
    unsigned short* __restrict__ wB1, unsigned short* __restrict__ wB2) {
    int idx = blockIdx.x * 256 + threadIdx.x;          // 0..73727
    const float* src = (idx < 36864) ? w1 : w2;
    unsigned short* dst = (idx < 36864) ? wB1 : wB2;
    int e = (idx < 36864) ? idx : idx - 36864;
    int j = e & 7;
    int lane = (e >> 3) & 63;
    int ct = (e >> 9) & 3;
    int kb = e >> 11;
    int co = ct * 16 + (lane & 15);
    int k = kb * 32 + ((lane >> 4) * 8) + j;
    int ci = k & 63;
    int tap = k >> 6;
    dst[e] = f2bf(src[(co * 64 + ci) * 9 + tap]);
}

// ---------------------------------------------------------------------------
// Stem: f1[b][p][co] = silu(bn(sum_ci x[b][ci][p] * W[co][ci]))  (NHWC bf16)
// Block: 128-px tile. Stage x-tile [128px][128ci] bf16 in LDS (XOR swizzle:
// granule g=ci>>3 stored at g^(px&15)). Wave wv: 64 co x 32 px (2 n-tiles).
__global__ __launch_bounds__(256) void stem_kernel(
    const float* __restrict__ x, const float* __restrict__ w,
    const float* __restrict__ scale, const float* __restrict__ shift,
    unsigned short* __restrict__ f1) {
    __shared__ __align__(16) unsigned short xt[128 * 128];   // 32 KB
    int b = blockIdx.y;
    int tid = threadIdx.x;
    int pbase = blockIdx.x * 128;
    int lane = tid & 63, wv = tid >> 6;
    int l15 = lane & 15, q = lane >> 4;

    // ---- stage x-tile: 16 independent float4 loads/thread, coalesced 512B/half-wave
    #pragma unroll
    for (int i = 0; i < 16; ++i) {
        int ci = i * 8 + (tid >> 5);
        int pxq = tid & 31;
        const float* xp = x + ((size_t)b * 128 + ci) * NPIX + pbase + pxq * 4;
        fx4 v = *(const fx4*)xp;
        #pragma unroll
        for (int j = 0; j < 4; ++j) {
            int px = pxq * 4 + j;
            xt[px * 128 + (((ci >> 3) ^ (px & 15)) * 8) + (ci & 7)] = f2bf(v[j]);
        }
    }

    // ---- weight A-frags (register resident): A[m=co][k=ci]
    short8 wf[4][4];     // [ct][kb]
    #pragma unroll
    for (int ct = 0; ct < 4; ++ct) {
        int co = ct * 16 + l15;
        #pragma unroll
        for (int kb = 0; kb < 4; ++kb) {
            const float* wp = w + co * 128 + kb * 32 + q * 8;
            fx4 a = *(const fx4*)wp;
            fx4 bv = *(const fx4*)(wp + 4);
            short8 f;
            #pragma unroll
            for (int j = 0; j < 4; ++j) f[j] = (short)f2bf(a[j]);
            #pragma unroll
            for (int j = 0; j < 4; ++j) f[j + 4] = (short)f2bf(bv[j]);
            wf[ct][kb] = f;
        }
    }
    float sc[4][4], sh[4][4];
    #pragma unroll
    for (int ct = 0; ct < 4; ++ct)
        #pragma unroll
        for (int r = 0; r < 4; ++r) {
            sc[ct][r] = scale[ct * 16 + q * 4 + r];
            sh[ct][r] = shift[ct * 16 + q * 4 + r];
        }

    __syncthreads();

    // ---- K loop from LDS
    floatx4 acc[4][2];
    floatx4 zf = {0.0f, 0.0f, 0.0f, 0.0f};
    #pragma unroll
    for (int ct = 0; ct < 4; ++ct)
        #pragma unroll
        for (int t = 0; t < 2; ++t) acc[ct][t] = zf;

    #pragma unroll
    for (int kb = 0; kb < 4; ++kb) {
        short8 xf[2];
        #pragma unroll
        for (int t = 0; t < 2; ++t) {
            int px = (wv * 2 + t) * 16 + l15;
            xf[t] = *(const short8*)(xt + px * 128 + (((kb * 4 + q) ^ (px & 15)) * 8));
        }
        #pragma unroll
        for (int ct = 0; ct < 4; ++ct)
            #pragma unroll
            for (int t = 0; t < 2; ++t)
                acc[ct][t] = __builtin_amdgcn_mfma_f32_16x16x32_bf16(
                    wf[ct][kb], xf[t], acc[ct][t], 0, 0, 0);
    }

    // ---- epilogue: BN+SiLU, lane holds 4 contiguous co -> ushort4 stores
    #pragma unroll
    for (int t = 0; t < 2; ++t) {
        int pg = pbase + (wv * 2 + t) * 16 + l15;
        unsigned short* dst = f1 + ((size_t)b * NPIX + pg) * 64;
        #pragma unroll
        for (int ct = 0; ct < 4; ++ct) {
            us4 v;
            #pragma unroll
            for (int r = 0; r < 4; ++r)
                v[r] = f2bf(silu_(acc[ct][t][r] * sc[ct][r] + sh[ct][r]));
            *(us4*)(dst + ct * 16 + q * 4) = v;
        }
    }
}

// ---------------------------------------------------------------------------
// 3x3 conv 64->64: block = 4 rows x 80 px. Stage input tile 6x82 px x 64 ci
// bf16 into LDS (zero halo at staging). Weights register-resident: wave wv
// owns co range [wv*16, wv*16+16). K-loop: pure ds_read_b128 + MFMA.
__global__ __launch_bounds__(256, 2) void conv3_kernel(
    const unsigned short* __restrict__ fin, const unsigned short* __restrict__ wB,
    const float* __restrict__ scale, const float* __restrict__ shift,
    unsigned short* __restrict__ fout) {
    __shared__ __align__(16) unsigned short tile[492 * 64];  // 61.5 KB
    int b = blockIdx.y;
    int y0 = blockIdx.x * 4;
    int tid = threadIdx.x;
    int lane = tid & 63, wv = tid >> 6;
    int l15 = lane & 15, q = lane >> 4;

    // ---- stage 6 rows x 82 cols x 64ci (3936 16B-chunks)
    const unsigned short* fb = fin + (size_t)b * NPIX * 64;
    #pragma unroll
    for (int i = 0; i < 16; ++i) {
        int cid = i * 256 + tid;
        if (cid < 3936) {
            int pixL = cid >> 3, chunk = cid & 7;
            int r = pixL / 82, c = pixL - r * 82;
            int gy = y0 - 1 + r, gx = c - 1;
            short8 v = {};
            if ((unsigned)gy < 80u && (unsigned)gx < 80u)
                v = *(const short8*)(fb + (size_t)(gy * 80 + gx) * 64 + chunk * 8);
            *(short8*)(tile + pixL * 64 + ((chunk ^ (pixL & 7)) * 8)) = v;
        }
    }

    // ---- weights: 18 A-frags, ct = wv
    short8 wreg[18];
    #pragma unroll
    for (int kb = 0; kb < 18; ++kb)
        wreg[kb] = *(const short8*)(wB + ((kb * 4 + wv) * 64 + lane) * 8);

    __syncthreads();

    floatx4 acc[20];
    floatx4 zf = {0.0f, 0.0f, 0.0f, 0.0f};
    #pragma unroll
    for (int pt = 0; pt < 20; ++pt) acc[pt] = zf;

    #pragma unroll
    for (int tap = 0; tap < 9; ++tap) {
        const int dy = tap / 3 - 1, dx = tap % 3 - 1;
        #pragma unroll
        for (int half = 0; half < 2; ++half) {
            short8 w8 = wreg[tap * 2 + half];
            #pragma unroll
            for (int pt = 0; pt < 20; ++pt) {
                const int r_o = pt / 5, c_o = (pt % 5) * 16;
                int pix = (r_o + 1 + dy) * 82 + c_o + l15 + 1 + dx;
                short8 bf8 = *(const short8*)(
                    tile + pix * 64 + (((half * 4 + q) ^ (pix & 7)) * 8));
                acc[pt] = __builtin_amdgcn_mfma_f32_16x16x32_bf16(
                    w8, bf8, acc[pt], 0, 0, 0);
            }
        }
    }

    // ---- epilogue: co = wv*16 + q*4 + r
    float sc4[4], sh4[4];
    #pragma unroll
    for (int r = 0; r < 4; ++r) {
        sc4[r] = scale[wv * 16 + q * 4 + r];
        sh4[r] = shift[wv * 16 + q * 4 + r];
    }
    #pragma unroll
    for (int pt = 0; pt < 20; ++pt) {
        const int r_o = pt / 5, c_o = (pt % 5) * 16;
        int pg = (y0 + r_o) * 80 + c_o + l15;
        us4 v;
        #pragma unroll
        for (int r = 0; r < 4; ++r)
            v[r] = f2bf(silu_(acc[pt][r] * sc4[r] + sh4[r]));
        *(us4*)(fout + ((size_t)b * NPIX + pg) * 64 + wv * 16 + q * 4) = v;
    }
}

// ---------------------------------------------------------------------------
// c2 conv + BN/SiLU + 1x1 heads + YOLOX decode. Same conv core; h tile reuses
// the staging LDS (barriered), head is a tiny K=64 MFMA, decode to fp32 out.
__global__ __launch_bounds__(256, 2) void conv_head_kernel(
    const unsigned short* __restrict__ fin, const unsigned short* __restrict__ wB,
    const float* __restrict__ scale, const float* __restrict__ shift,
    const float* __restrict__ reg_w, const float* __restrict__ reg_b,
    const float* __restrict__ obj_w, const float* __restrict__ obj_b,
    float* __restrict__ out) {
    __shared__ __align__(16) unsigned short tile[492 * 64];
    int b = blockIdx.y;
    int y0 = blockIdx.x * 4;
    int tid = threadIdx.x;
    int lane = tid & 63, wv = tid >> 6;
    int l15 = lane & 15, q = lane >> 4;

    const unsigned short* fb = fin + (size_t)b * NPIX * 64;
    #pragma unroll
    for (int i = 0; i < 16; ++i) {
        int cid = i * 256 + tid;
        if (cid < 3936) {
            int pixL = cid >> 3, chunk = cid & 7;
            int r = pixL / 82, c = pixL - r * 82;
            int gy = y0 - 1 + r, gx = c - 1;
            short8 v = {};
            if ((unsigned)gy < 80u && (unsigned)gx < 80u)
                v = *(const short8*)(fb + (size_t)(gy * 80 + gx) * 64 + chunk * 8);
            *(short8*)(tile + pixL * 64 + ((chunk ^ (pixL & 7)) * 8)) = v;
        }
    }

    short8 wreg[18];
    #pragma unroll
    for (int kb = 0; kb < 18; ++kb)
        wreg[kb] = *(const short8*)(wB + ((kb * 4 + wv) * 64 + lane) * 8);

    __syncthreads();

    floatx4 acc[20];
    floatx4 zf = {0.0f, 0.0f, 0.0f, 0.0f};
    #pragma unroll
    for (int pt = 0; pt < 20; ++pt) acc[pt] = zf;

    #pragma unroll
    for (int tap = 0; tap < 9; ++tap) {
        const int dy = tap / 3 - 1, dx = tap % 3 - 1;
        #pragma unroll
        for (int half = 0; half < 2; ++half) {
            short8 w8 = wreg[tap * 2 + half];
            #pragma unroll
            for (int pt = 0; pt < 20; ++pt) {
                const int r_o = pt / 5, c_o = (pt % 5) * 16;
                int pix = (r_o + 1 + dy) * 82 + c_o + l15 + 1 + dx;
                short8 bf8 = *(const short8*)(
                    tile + pix * 64 + (((half * 4 + q) ^ (pix & 7)) * 8));
                acc[pt] = __builtin_amdgcn_mfma_f32_16x16x32_bf16(
                    w8, bf8, acc[pt], 0, 0, 0);
            }
        }
    }

    __syncthreads();   // all waves done reading tile -> safe to overwrite with h

    // ---- BN+SiLU -> h[pix 0..319][co 0..63] in LDS (swizzled like tile)
    float sc4[4], sh4[4];
    #pragma unroll
    for (int r = 0; r < 4; ++r) {
        sc4[r] = scale[wv * 16 + q * 4 + r];
        sh4[r] = shift[wv * 16 + q * 4 + r];
    }
    int gco = (wv * 2 + (q >> 1));          // 8-ushort granule index of co base
    #pragma unroll
    for (int pt = 0; pt < 20; ++pt) {
        const int r_o = pt / 5, c_o = (pt % 5) * 16;
        int pix = r_o * 80 + c_o + l15;     // block-local pixel 0..319
        us4 v;
        #pragma unroll
        for (int r = 0; r < 4; ++r)
            v[r] = f2bf(silu_(acc[pt][r] * sc4[r] + sh4[r]));
        *(us4*)(tile + pix * 64 + ((gco ^ (pix & 7)) * 8) + (q & 1) * 4) = v;
    }

    // head B-frags: B[k=co][n] = reg_w[n][co] (n<4), obj_w[co] (n==4), else 0
    short8 hbf[2];
    #pragma unroll
    for (int kb2 = 0; kb2 < 2; ++kb2) {
        int k0 = kb2 * 32 + q * 8;
        short8 f = {};
        if (l15 < 4) {
            #pragma unroll
            for (int j = 0; j < 8; ++j) f[j] = (short)f2bf(reg_w[l15 * 64 + k0 + j]);
        } else if (l15 == 4) {
            #pragma unroll
            for (int j = 0; j < 8; ++j) f[j] = (short)f2bf(obj_w[k0 + j]);
        }
        hbf[kb2] = f;
    }

    __syncthreads();

    // ---- head MFMA: wave handles m-tiles wv*5 .. wv*5+4 (16 px each)
    floatx4 acc5[5];
    #pragma unroll
    for (int t = 0; t < 5; ++t) acc5[t] = zf;
    #pragma unroll
    for (int t = 0; t < 5; ++t) {
        int mt = wv * 5 + t;
        #pragma unroll
        for (int kb2 = 0; kb2 < 2; ++kb2) {
            int pix = mt * 16 + l15;
            short8 a = *(const short8*)(
                tile + pix * 64 + (((kb2 * 4 + q) ^ (pix & 7)) * 8));
            acc5[t] = __builtin_amdgcn_mfma_f32_16x16x32_bf16(
                a, hbf[kb2], acc5[t], 0, 0, 0);
        }
    }

    float bias = 0.0f;
    if (l15 < 4) bias = reg_b[l15];
    else if (l15 == 4) bias = obj_b[0];

    #pragma unroll
    for (int t = 0; t < 5; ++t) {
        int mt = wv * 5 + t;
        #pragma unroll
        for (int r = 0; r < 4; ++r) {
            int pixL = mt * 16 + q * 4 + r;       // block-local pixel
            if (l15 < 5) {
                float v = acc5[t][r] + bias;
                float gx = (float)(pixL % 80);
                float gy = (float)(y0 + pixL / 80);
                float o;
                if (l15 == 0)      o = (v + gx) * 32.0f;
                else if (l15 == 1) o = (v + gy) * 32.0f;
                else if (l15 < 4)  o = __expf(v) * 32.0f;
                else               o = 1.0f / (1.0f + __expf(-v));
                out[((size_t)b * NPIX + y0 * 80 + pixL) * 5 + l15] = o;
            }
        }
    }
}

// ---------------------------------------------------------------------------
extern "C" void kernel_launch(void* const* d_in, const int* in_sizes, int n_in,
                              void* d_out, int out_size, void* d_ws, size_t ws_size,
                              hipStream_t stream) {
    const float* x          = (const float*)d_in[0];
    const float* stem_w     = (const float*)d_in[1];
    const float* stem_scale = (const float*)d_in[2];
    const float* stem_shift = (const float*)d_in[3];
    const float* c1_w       = (const float*)d_in[4];
    const float* c1_scale   = (const float*)d_in[5];
    const float* c1_shift   = (const float*)d_in[6];
    const float* c2_w       = (const float*)d_in[7];
    const float* c2_scale   = (const float*)d_in[8];
    const float* c2_shift   = (const float*)d_in[9];
    const float* reg_w      = (const float*)d_in[10];
    const float* reg_b      = (const float*)d_in[11];
    const float* obj_w      = (const float*)d_in[12];
    const float* obj_b      = (const float*)d_in[13];
    float* out = (float*)d_out;

    // ws layout (ushort units): wB1[36864] | wB2[36864] | f1[64*6400*64] | f2[same]
    const size_t needed = ((size_t)73728 + 2 * (size_t)64 * NPIX * 64) * 2;
    if (ws_size < needed) return;

    unsigned short* ws  = (unsigned short*)d_ws;
    unsigned short* wB1 = ws;
    unsigned short* wB2 = ws + 36864;
    unsigned short* f1  = ws + 73728;
    unsigned short* f2  = f1 + (size_t)64 * NPIX * 64;

    rearr_w_kernel<<<288, 256, 0, stream>>>(c1_w, c2_w, wB1, wB2);
    stem_kernel<<<dim3(50, 64), 256, 0, stream>>>(x, stem_w, stem_scale, stem_shift, f1);
    conv3_kernel<<<dim3(20, 64), 256, 0, stream>>>(f1, wB1, c1_scale, c1_shift, f2);
    conv_head_kernel<<<dim3(20, 64), 256, 0, stream>>>(f2, wB2, c2_scale, c2_shift,
                                                       reg_w, reg_b, obj_w, obj_b, out);
}

// Round 4
// 498.898 us; speedup vs baseline: 1.6855x; 1.6855x over previous
//
#include <hip/hip_runtime.h>
#include <cstdint>

// SREChead: stem 1x1 (128->64) + 2x 3x3 (64->64), each BN+SiLU, then 1x1
// reg(4)/obj(1) heads + YOLOX decode. B=64, 80x80, stride 32.
// R4: granule-major LDS tiles ([g][pix][8] bf16, padded granule stride ->
// conflict-free, addresses linear in pix); windowed weight fragments to kill
// the R3 register spills (R3: 913MB HBM traffic/conv = spill storm).

typedef short short8 __attribute__((ext_vector_type(8)));
typedef float floatx4 __attribute__((ext_vector_type(4)));
typedef float fx4 __attribute__((ext_vector_type(4)));
typedef unsigned short us4 __attribute__((ext_vector_type(4)));

#define NPIX 6400
// conv tile: 6 rows x 82 cols = 492 pixel slots, granule stride 494 (pad)
#define CGS 3952            // 494 * 8 ushorts per granule
// stem tile: 128 px, 16 granules, stride 128*8 ushorts
#define SGS 1024

static __device__ __forceinline__ unsigned short f2bf(float f) {
    unsigned u = __builtin_bit_cast(unsigned, f);
    u += 0x7fffu + ((u >> 16) & 1u);      // round-to-nearest-even
    return (unsigned short)(u >> 16);
}

static __device__ __forceinline__ float silu_(float v) {
    return v / (1.0f + __expf(-v));
}

// ---------------------------------------------------------------------------
// Rearrange weights to bf16 MFMA A-frag order.
//  wS  [kb(4)][ct(4)][lane][8]  from stem_w [64co][128ci]      (8192 el)
//  wB1 [kb(18)][ct(4)][lane][8] from c1_w [64co][64ci][3][3]   (36864 el)
//  wB2 same from c2_w
// co = ct*16+(lane&15); k = kb*32+(lane>>4)*8+j; conv: ci=k&63, tap=k>>6.
__global__ __launch_bounds__(256) void rearr_w_kernel(
    const float* __restrict__ ws_, const float* __restrict__ w1,
    const float* __restrict__ w2,
    unsigned short* __restrict__ wS, unsigned short* __restrict__ wB1,
    unsigned short* __restrict__ wB2) {
    int idx = blockIdx.x * 256 + threadIdx.x;          // 0..81919
    if (idx < 8192) {
        int e = idx;
        int j = e & 7, lane = (e >> 3) & 63, ct = (e >> 9) & 3, kb = e >> 11;
        int co = ct * 16 + (lane & 15);
        int ci = kb * 32 + ((lane >> 4) * 8) + j;
        wS[e] = f2bf(ws_[co * 128 + ci]);
        return;
    }
    idx -= 8192;
    const float* src = (idx < 36864) ? w1 : w2;
    unsigned short* dst = (idx < 36864) ? wB1 : wB2;
    int e = (idx < 36864) ? idx : idx - 36864;
    int j = e & 7, lane = (e >> 3) & 63, ct = (e >> 9) & 3, kb = e >> 11;
    int co = ct * 16 + (lane & 15);
    int k = kb * 32 + ((lane >> 4) * 8) + j;
    int ci = k & 63, tap = k >> 6;
    dst[e] = f2bf(src[(co * 64 + ci) * 9 + tap]);
}

// ---------------------------------------------------------------------------
// Stem: f1[b][p][co] = silu(bn(sum_ci x[b][ci][p] * W[co][ci]))  (NHWC bf16)
// Block: 128-px tile. LDS xt granule-major [g(16)][px(128)][8] (32 KB).
// Staging: thread owns (g,px), 8 coalesced strided dword loads -> 1 b128 store.
__global__ __launch_bounds__(256) void stem_kernel(
    const float* __restrict__ x, const unsigned short* __restrict__ wS,
    const float* __restrict__ scale, const float* __restrict__ shift,
    unsigned short* __restrict__ f1) {
    __shared__ __align__(16) unsigned short xt[16 * SGS];   // 32 KB
    int b = blockIdx.y;
    int tid = threadIdx.x;
    int pbase = blockIdx.x * 128;
    int lane = tid & 63, wv = tid >> 6;
    int l15 = lane & 15, q = lane >> 4;

    #pragma unroll
    for (int k = 0; k < 8; ++k) {
        int item = k * 256 + tid;
        int g = item >> 7, px = item & 127;
        const float* xp = x + ((size_t)b * 128 + g * 8) * NPIX + pbase + px;
        unsigned short tmp[8];
        #pragma unroll
        for (int j = 0; j < 8; ++j) tmp[j] = f2bf(xp[j * NPIX]);
        *(short8*)(xt + g * SGS + px * 8) = *(const short8*)tmp;
    }

    float sc[4][4], sh[4][4];
    #pragma unroll
    for (int ct = 0; ct < 4; ++ct)
        #pragma unroll
        for (int r = 0; r < 4; ++r) {
            sc[ct][r] = scale[ct * 16 + q * 4 + r];
            sh[ct][r] = shift[ct * 16 + q * 4 + r];
        }

    __syncthreads();

    floatx4 acc[4][2];   // [ct][t]
    floatx4 zf = {0.0f, 0.0f, 0.0f, 0.0f};
    #pragma unroll
    for (int ct = 0; ct < 4; ++ct)
        #pragma unroll
        for (int t = 0; t < 2; ++t) acc[ct][t] = zf;

    #pragma unroll
    for (int kb = 0; kb < 4; ++kb) {
        short8 wf[4];
        #pragma unroll
        for (int ct = 0; ct < 4; ++ct)
            wf[ct] = *(const short8*)(wS + ((kb * 4 + ct) * 64 + lane) * 8);
        short8 xf[2];
        #pragma unroll
        for (int t = 0; t < 2; ++t) {
            int px = (wv * 2 + t) * 16 + l15;
            xf[t] = *(const short8*)(xt + (kb * 4 + q) * SGS + px * 8);
        }
        #pragma unroll
        for (int ct = 0; ct < 4; ++ct)
            #pragma unroll
            for (int t = 0; t < 2; ++t)
                acc[ct][t] = __builtin_amdgcn_mfma_f32_16x16x32_bf16(
                    wf[ct], xf[t], acc[ct][t], 0, 0, 0);
    }

    #pragma unroll
    for (int t = 0; t < 2; ++t) {
        int pg = pbase + (wv * 2 + t) * 16 + l15;
        unsigned short* dst = f1 + ((size_t)b * NPIX + pg) * 64;
        #pragma unroll
        for (int ct = 0; ct < 4; ++ct) {
            us4 v;
            #pragma unroll
            for (int r = 0; r < 4; ++r)
                v[r] = f2bf(silu_(acc[ct][t][r] * sc[ct][r] + sh[ct][r]));
            *(us4*)(dst + ct * 16 + q * 4) = v;
        }
    }
}

// ---------------------------------------------------------------------------
// Shared conv core: stage 6x82x64ci tile (granule-major), 3x3x2 K-loop with
// per-row weight windows (6 frags live). Wave wv owns co [wv*16, wv*16+16).
static __device__ __forceinline__ void conv_core(
    const unsigned short* __restrict__ fin, const unsigned short* __restrict__ wB,
    unsigned short* tile, floatx4* acc, int b, int y0,
    int tid, int lane, int wv, int l15, int q) {
    const unsigned short* fb = fin + (size_t)b * NPIX * 64;
    #pragma unroll
    for (int i = 0; i < 16; ++i) {
        int cid = i * 256 + tid;
        if (cid < 3936) {
            int pixL = cid >> 3, chunk = cid & 7;
            int r = pixL / 82, c = pixL - r * 82;
            int gy = y0 - 1 + r, gx = c - 1;
            short8 v = {};
            if ((unsigned)gy < 80u && (unsigned)gx < 80u)
                v = *(const short8*)(fb + (size_t)(gy * 80 + gx) * 64 + chunk * 8);
            *(short8*)(tile + chunk * CGS + pixL * 8) = v;
        }
    }

    __syncthreads();

    floatx4 zf = {0.0f, 0.0f, 0.0f, 0.0f};
    #pragma unroll
    for (int pt = 0; pt < 20; ++pt) acc[pt] = zf;

    #pragma unroll
    for (int trow = 0; trow < 3; ++trow) {
        short8 wrow[6];           // taps trow*3..+2, both halves: 24 VGPR window
        #pragma unroll
        for (int i = 0; i < 6; ++i)
            wrow[i] = *(const short8*)(wB + (((trow * 6 + i) * 4 + wv) * 64 + lane) * 8);
        const int dy = trow - 1;
        #pragma unroll
        for (int tc = 0; tc < 3; ++tc) {
            const int dx = tc - 1;
            #pragma unroll
            for (int half = 0; half < 2; ++half) {
                short8 w8 = wrow[tc * 2 + half];
                #pragma unroll
                for (int pt = 0; pt < 20; ++pt) {
                    const int r_o = pt / 5, c_o = (pt % 5) * 16;
                    int pix = (r_o + 1 + dy) * 82 + c_o + l15 + 1 + dx;
                    short8 b8 = *(const short8*)(tile + (half * 4 + q) * CGS + pix * 8);
                    acc[pt] = __builtin_amdgcn_mfma_f32_16x16x32_bf16(
                        w8, b8, acc[pt], 0, 0, 0);
                }
            }
        }
    }
}

// ---------------------------------------------------------------------------
__global__ __launch_bounds__(256) void conv3_kernel(
    const unsigned short* __restrict__ fin, const unsigned short* __restrict__ wB,
    const float* __restrict__ scale, const float* __restrict__ shift,
    unsigned short* __restrict__ fout) {
    __shared__ __align__(16) unsigned short tile[8 * CGS];  // 63232 B
    int b = blockIdx.y, y0 = blockIdx.x * 4;
    int tid = threadIdx.x;
    int lane = tid & 63, wv = tid >> 6;
    int l15 = lane & 15, q = lane >> 4;

    floatx4 acc[20];
    conv_core(fin, wB, tile, acc, b, y0, tid, lane, wv, l15, q);

    float sc4[4], sh4[4];
    #pragma unroll
    for (int r = 0; r < 4; ++r) {
        sc4[r] = scale[wv * 16 + q * 4 + r];
        sh4[r] = shift[wv * 16 + q * 4 + r];
    }
    #pragma unroll
    for (int pt = 0; pt < 20; ++pt) {
        const int r_o = pt / 5, c_o = (pt % 5) * 16;
        int pg = (y0 + r_o) * 80 + c_o + l15;
        us4 v;
        #pragma unroll
        for (int r = 0; r < 4; ++r)
            v[r] = f2bf(silu_(acc[pt][r] * sc4[r] + sh4[r]));
        *(us4*)(fout + ((size_t)b * NPIX + pg) * 64 + wv * 16 + q * 4) = v;
    }
}

// ---------------------------------------------------------------------------
__global__ __launch_bounds__(256) void conv_head_kernel(
    const unsigned short* __restrict__ fin, const unsigned short* __restrict__ wB,
    const float* __restrict__ scale, const float* __restrict__ shift,
    const float* __restrict__ reg_w, const float* __restrict__ reg_b,
    const float* __restrict__ obj_w, const float* __restrict__ obj_b,
    float* __restrict__ out) {
    __shared__ __align__(16) unsigned short tile[8 * CGS];
    int b = blockIdx.y, y0 = blockIdx.x * 4;
    int tid = threadIdx.x;
    int lane = tid & 63, wv = tid >> 6;
    int l15 = lane & 15, q = lane >> 4;

    floatx4 acc[20];
    conv_core(fin, wB, tile, acc, b, y0, tid, lane, wv, l15, q);

    __syncthreads();   // all waves done reading tile -> safe to overwrite with h

    // BN+SiLU -> h[pix 0..319][co] granule-major in the same LDS
    float sc4[4], sh4[4];
    #pragma unroll
    for (int r = 0; r < 4; ++r) {
        sc4[r] = scale[wv * 16 + q * 4 + r];
        sh4[r] = shift[wv * 16 + q * 4 + r];
    }
    int gco = wv * 2 + (q >> 1);            // granule of this lane's co base
    #pragma unroll
    for (int pt = 0; pt < 20; ++pt) {
        const int r_o = pt / 5, c_o = (pt % 5) * 16;
        int pix = r_o * 80 + c_o + l15;     // block-local pixel 0..319
        us4 v;
        #pragma unroll
        for (int r = 0; r < 4; ++r)
            v[r] = f2bf(silu_(acc[pt][r] * sc4[r] + sh4[r]));
        *(us4*)(tile + gco * CGS + pix * 8 + (q & 1) * 4) = v;
    }

    // head B-frags: B[k=co][n] = reg_w[n][co] (n<4), obj_w[co] (n==4), else 0
    short8 hbf[2];
    #pragma unroll
    for (int kb2 = 0; kb2 < 2; ++kb2) {
        int k0 = kb2 * 32 + q * 8;
        short8 f = {};
        if (l15 < 4) {
            #pragma unroll
            for (int j = 0; j < 8; ++j) f[j] = (short)f2bf(reg_w[l15 * 64 + k0 + j]);
        } else if (l15 == 4) {
            #pragma unroll
            for (int j = 0; j < 8; ++j) f[j] = (short)f2bf(obj_w[k0 + j]);
        }
        hbf[kb2] = f;
    }

    __syncthreads();

    floatx4 zf = {0.0f, 0.0f, 0.0f, 0.0f};
    floatx4 acc5[5];
    #pragma unroll
    for (int t = 0; t < 5; ++t) acc5[t] = zf;
    #pragma unroll
    for (int t = 0; t < 5; ++t) {
        int mt = wv * 5 + t;
        #pragma unroll
        for (int kb2 = 0; kb2 < 2; ++kb2) {
            int pix = mt * 16 + l15;
            short8 a = *(const short8*)(tile + (kb2 * 4 + q) * CGS + pix * 8);
            acc5[t] = __builtin_amdgcn_mfma_f32_16x16x32_bf16(
                a, hbf[kb2], acc5[t], 0, 0, 0);
        }
    }

    float bias = 0.0f;
    if (l15 < 4) bias = reg_b[l15];
    else if (l15 == 4) bias = obj_b[0];

    #pragma unroll
    for (int t = 0; t < 5; ++t) {
        int mt = wv * 5 + t;
        #pragma unroll
        for (int r = 0; r < 4; ++r) {
            int pixL = mt * 16 + q * 4 + r;
            if (l15 < 5) {
                float v = acc5[t][r] + bias;
                float gx = (float)(pixL % 80);
                float gy = (float)(y0 + pixL / 80);
                float o;
                if (l15 == 0)      o = (v + gx) * 32.0f;
                else if (l15 == 1) o = (v + gy) * 32.0f;
                else if (l15 < 4)  o = __expf(v) * 32.0f;
                else               o = 1.0f / (1.0f + __expf(-v));
                out[((size_t)b * NPIX + y0 * 80 + pixL) * 5 + l15] = o;
            }
        }
    }
}

// ---------------------------------------------------------------------------
extern "C" void kernel_launch(void* const* d_in, const int* in_sizes, int n_in,
                              void* d_out, int out_size, void* d_ws, size_t ws_size,
                              hipStream_t stream) {
    const float* x          = (const float*)d_in[0];
    const float* stem_w     = (const float*)d_in[1];
    const float* stem_scale = (const float*)d_in[2];
    const float* stem_shift = (const float*)d_in[3];
    const float* c1_w       = (const float*)d_in[4];
    const float* c1_scale   = (const float*)d_in[5];
    const float* c1_shift   = (const float*)d_in[6];
    const float* c2_w       = (const float*)d_in[7];
    const float* c2_scale   = (const float*)d_in[8];
    const float* c2_shift   = (const float*)d_in[9];
    const float* reg_w      = (const float*)d_in[10];
    const float* reg_b      = (const float*)d_in[11];
    const float* obj_w      = (const float*)d_in[12];
    const float* obj_b      = (const float*)d_in[13];
    float* out = (float*)d_out;

    // ws (ushort units): wS[8192] | wB1[36864] | wB2[36864] | f1 | f2
    const size_t needed = ((size_t)8192 + 73728 + 2 * (size_t)64 * NPIX * 64) * 2;
    if (ws_size < needed) return;

    unsigned short* ws  = (unsigned short*)d_ws;
    unsigned short* wS  = ws;
    unsigned short* wB1 = ws + 8192;
    unsigned short* wB2 = wB1 + 36864;
    unsigned short* f1  = wB2 + 36864;
    unsigned short* f2  = f1 + (size_t)64 * NPIX * 64;

    rearr_w_kernel<<<320, 256, 0, stream>>>(stem_w, c1_w, c2_w, wS, wB1, wB2);
    stem_kernel<<<dim3(50, 64), 256, 0, stream>>>(x, wS, stem_scale, stem_shift, f1);
    conv3_kernel<<<dim3(20, 64), 256, 0, stream>>>(f1, wB1, c1_scale, c1_shift, f2);
    conv_head_kernel<<<dim3(20, 64), 256, 0, stream>>>(f2, wB2, c2_scale, c2_shift,
                                                       reg_w, reg_b, obj_w, obj_b, out);
}

// Round 5
// 450.341 us; speedup vs baseline: 1.8672x; 1.1078x over previous
//
#include <hip/hip_runtime.h>
#include <cstdint>

// SREChead: stem 1x1 (128->64) + 2x 3x3 (64->64), each BN+SiLU, then 1x1
// reg(4)/obj(1) heads + YOLOX decode. B=64, 80x80, stride 32.
// R5: conv waves own 2 co-tiles (N-register-blocking) -> each LDS B-read
// feeds 2 MFMAs, halving LDS-port traffic (R4 was 1:1, read-issue-bound).
// Granule-major LDS tiles ([g][pix][8] bf16, padded stride = conflict-free).

typedef short short8 __attribute__((ext_vector_type(8)));
typedef float floatx4 __attribute__((ext_vector_type(4)));
typedef float fx4 __attribute__((ext_vector_type(4)));
typedef unsigned short us4 __attribute__((ext_vector_type(4)));

#define NPIX 6400
// conv tile: 6 rows x 82 cols = 492 pixel slots, granule stride 494 (pad)
#define CGS 3952            // 494 * 8 ushorts per granule
// stem tile: 128 px, 16 granules, stride 128*8 ushorts
#define SGS 1024

static __device__ __forceinline__ unsigned short f2bf(float f) {
    unsigned u = __builtin_bit_cast(unsigned, f);
    u += 0x7fffu + ((u >> 16) & 1u);      // round-to-nearest-even
    return (unsigned short)(u >> 16);
}

static __device__ __forceinline__ float silu_(float v) {
    return v / (1.0f + __expf(-v));
}

// ---------------------------------------------------------------------------
// Rearrange weights to bf16 MFMA A-frag order.
//  wS  [kb(4)][ct(4)][lane][8]  from stem_w [64co][128ci]      (8192 el)
//  wB1 [kb(18)][ct(4)][lane][8] from c1_w [64co][64ci][3][3]   (36864 el)
//  wB2 same from c2_w
// co = ct*16+(lane&15); k = kb*32+(lane>>4)*8+j; conv: ci=k&63, tap=k>>6.
__global__ __launch_bounds__(256) void rearr_w_kernel(
    const float* __restrict__ ws_, const float* __restrict__ w1,
    const float* __restrict__ w2,
    unsigned short* __restrict__ wS, unsigned short* __restrict__ wB1,
    unsigned short* __restrict__ wB2) {
    int idx = blockIdx.x * 256 + threadIdx.x;          // 0..81919
    if (idx < 8192) {
        int e = idx;
        int j = e & 7, lane = (e >> 3) & 63, ct = (e >> 9) & 3, kb = e >> 11;
        int co = ct * 16 + (lane & 15);
        int ci = kb * 32 + ((lane >> 4) * 8) + j;
        wS[e] = f2bf(ws_[co * 128 + ci]);
        return;
    }
    idx -= 8192;
    const float* src = (idx < 36864) ? w1 : w2;
    unsigned short* dst = (idx < 36864) ? wB1 : wB2;
    int e = (idx < 36864) ? idx : idx - 36864;
    int j = e & 7, lane = (e >> 3) & 63, ct = (e >> 9) & 3, kb = e >> 11;
    int co = ct * 16 + (lane & 15);
    int k = kb * 32 + ((lane >> 4) * 8) + j;
    int ci = k & 63, tap = k >> 6;
    dst[e] = f2bf(src[(co * 64 + ci) * 9 + tap]);
}

// ---------------------------------------------------------------------------
// Stem: f1[b][p][co] = silu(bn(sum_ci x[b][ci][p] * W[co][ci]))  (NHWC bf16)
// Block: 128-px tile. LDS xt granule-major [g(16)][px(128)][8] (32 KB).
__global__ __launch_bounds__(256) void stem_kernel(
    const float* __restrict__ x, const unsigned short* __restrict__ wS,
    const float* __restrict__ scale, const float* __restrict__ shift,
    unsigned short* __restrict__ f1) {
    __shared__ __align__(16) unsigned short xt[16 * SGS];   // 32 KB
    int b = blockIdx.y;
    int tid = threadIdx.x;
    int pbase = blockIdx.x * 128;
    int lane = tid & 63, wv = tid >> 6;
    int l15 = lane & 15, q = lane >> 4;

    #pragma unroll
    for (int k = 0; k < 8; ++k) {
        int item = k * 256 + tid;
        int g = item >> 7, px = item & 127;
        const float* xp = x + ((size_t)b * 128 + g * 8) * NPIX + pbase + px;
        unsigned short tmp[8];
        #pragma unroll
        for (int j = 0; j < 8; ++j) tmp[j] = f2bf(xp[j * NPIX]);
        *(short8*)(xt + g * SGS + px * 8) = *(const short8*)tmp;
    }

    float sc[4][4], sh[4][4];
    #pragma unroll
    for (int ct = 0; ct < 4; ++ct)
        #pragma unroll
        for (int r = 0; r < 4; ++r) {
            sc[ct][r] = scale[ct * 16 + q * 4 + r];
            sh[ct][r] = shift[ct * 16 + q * 4 + r];
        }

    __syncthreads();

    floatx4 acc[4][2];   // [ct][t]
    floatx4 zf = {0.0f, 0.0f, 0.0f, 0.0f};
    #pragma unroll
    for (int ct = 0; ct < 4; ++ct)
        #pragma unroll
        for (int t = 0; t < 2; ++t) acc[ct][t] = zf;

    #pragma unroll
    for (int kb = 0; kb < 4; ++kb) {
        short8 wf[4];
        #pragma unroll
        for (int ct = 0; ct < 4; ++ct)
            wf[ct] = *(const short8*)(wS + ((kb * 4 + ct) * 64 + lane) * 8);
        short8 xf[2];
        #pragma unroll
        for (int t = 0; t < 2; ++t) {
            int px = (wv * 2 + t) * 16 + l15;
            xf[t] = *(const short8*)(xt + (kb * 4 + q) * SGS + px * 8);
        }
        #pragma unroll
        for (int ct = 0; ct < 4; ++ct)
            #pragma unroll
            for (int t = 0; t < 2; ++t)
                acc[ct][t] = __builtin_amdgcn_mfma_f32_16x16x32_bf16(
                    wf[ct], xf[t], acc[ct][t], 0, 0, 0);
    }

    #pragma unroll
    for (int t = 0; t < 2; ++t) {
        int pg = pbase + (wv * 2 + t) * 16 + l15;
        unsigned short* dst = f1 + ((size_t)b * NPIX + pg) * 64;
        #pragma unroll
        for (int ct = 0; ct < 4; ++ct) {
            us4 v;
            #pragma unroll
            for (int r = 0; r < 4; ++r)
                v[r] = f2bf(silu_(acc[ct][t][r] * sc[ct][r] + sh[ct][r]));
            *(us4*)(dst + ct * 16 + q * 4) = v;
        }
    }
}

// ---------------------------------------------------------------------------
// Conv core with 2-ct N-blocking. Wave wv: co tiles {ct0, ct0+1} where
// ct0=(wv&1)*2; pixel rows rbase=(wv>>1)*2 .. rbase+1 (10 m-tiles).
// Each LDS B-read feeds 2 MFMAs. acc layout: acc[c][pt], pt 0..9.
static __device__ __forceinline__ void conv_core(
    const unsigned short* __restrict__ fin, const unsigned short* __restrict__ wB,
    unsigned short* tile, floatx4 (*acc)[10], int b, int y0,
    int tid, int lane, int wv, int l15, int q, int ct0, int rbase) {
    const unsigned short* fb = fin + (size_t)b * NPIX * 64;
    #pragma unroll
    for (int i = 0; i < 16; ++i) {
        int cid = i * 256 + tid;
        if (cid < 3936) {
            int pixL = cid >> 3, chunk = cid & 7;
            int r = pixL / 82, c = pixL - r * 82;
            int gy = y0 - 1 + r, gx = c - 1;
            short8 v = {};
            if ((unsigned)gy < 80u && (unsigned)gx < 80u)
                v = *(const short8*)(fb + (size_t)(gy * 80 + gx) * 64 + chunk * 8);
            *(short8*)(tile + chunk * CGS + pixL * 8) = v;
        }
    }

    __syncthreads();

    floatx4 zf = {0.0f, 0.0f, 0.0f, 0.0f};
    #pragma unroll
    for (int c = 0; c < 2; ++c)
        #pragma unroll
        for (int pt = 0; pt < 10; ++pt) acc[c][pt] = zf;

    #pragma unroll
    for (int trow = 0; trow < 3; ++trow) {
        short8 wrow[2][6];        // [ct][tc*2+half]: 48 VGPR window
        #pragma unroll
        for (int i = 0; i < 6; ++i)
            #pragma unroll
            for (int c = 0; c < 2; ++c)
                wrow[c][i] = *(const short8*)(
                    wB + (((trow * 6 + i) * 4 + ct0 + c) * 64 + lane) * 8);
        const int dy = trow - 1;
        #pragma unroll
        for (int tc = 0; tc < 3; ++tc) {
            const int dx = tc - 1;
            #pragma unroll
            for (int half = 0; half < 2; ++half) {
                short8 w0 = wrow[0][tc * 2 + half];
                short8 w1 = wrow[1][tc * 2 + half];
                #pragma unroll
                for (int pt = 0; pt < 10; ++pt) {
                    const int r_o = rbase + pt / 5, c_o = (pt % 5) * 16;
                    int pix = (r_o + 1 + dy) * 82 + c_o + l15 + 1 + dx;
                    short8 b8 = *(const short8*)(tile + (half * 4 + q) * CGS + pix * 8);
                    acc[0][pt] = __builtin_amdgcn_mfma_f32_16x16x32_bf16(
                        w0, b8, acc[0][pt], 0, 0, 0);
                    acc[1][pt] = __builtin_amdgcn_mfma_f32_16x16x32_bf16(
                        w1, b8, acc[1][pt], 0, 0, 0);
                }
            }
        }
    }
}

// ---------------------------------------------------------------------------
__global__ __launch_bounds__(256, 2) void conv3_kernel(
    const unsigned short* __restrict__ fin, const unsigned short* __restrict__ wB,
    const float* __restrict__ scale, const float* __restrict__ shift,
    unsigned short* __restrict__ fout) {
    __shared__ __align__(16) unsigned short tile[8 * CGS];  // 63232 B
    int b = blockIdx.y, y0 = blockIdx.x * 4;
    int tid = threadIdx.x;
    int lane = tid & 63, wv = tid >> 6;
    int l15 = lane & 15, q = lane >> 4;
    int ct0 = (wv & 1) * 2, rbase = (wv >> 1) * 2;

    floatx4 acc[2][10];
    conv_core(fin, wB, tile, acc, b, y0, tid, lane, wv, l15, q, ct0, rbase);

    float sc4[2][4], sh4[2][4];
    #pragma unroll
    for (int c = 0; c < 2; ++c)
        #pragma unroll
        for (int r = 0; r < 4; ++r) {
            sc4[c][r] = scale[(ct0 + c) * 16 + q * 4 + r];
            sh4[c][r] = shift[(ct0 + c) * 16 + q * 4 + r];
        }
    #pragma unroll
    for (int pt = 0; pt < 10; ++pt) {
        const int r_o = rbase + pt / 5, c_o = (pt % 5) * 16;
        int pg = (y0 + r_o) * 80 + c_o + l15;
        unsigned short* dst = fout + ((size_t)b * NPIX + pg) * 64;
        #pragma unroll
        for (int c = 0; c < 2; ++c) {
            us4 v;
            #pragma unroll
            for (int r = 0; r < 4; ++r)
                v[r] = f2bf(silu_(acc[c][pt][r] * sc4[c][r] + sh4[c][r]));
            *(us4*)(dst + (ct0 + c) * 16 + q * 4) = v;
        }
    }
}

// ---------------------------------------------------------------------------
__global__ __launch_bounds__(256, 2) void conv_head_kernel(
    const unsigned short* __restrict__ fin, const unsigned short* __restrict__ wB,
    const float* __restrict__ scale, const float* __restrict__ shift,
    const float* __restrict__ reg_w, const float* __restrict__ reg_b,
    const float* __restrict__ obj_w, const float* __restrict__ obj_b,
    float* __restrict__ out) {
    __shared__ __align__(16) unsigned short tile[8 * CGS];
    int b = blockIdx.y, y0 = blockIdx.x * 4;
    int tid = threadIdx.x;
    int lane = tid & 63, wv = tid >> 6;
    int l15 = lane & 15, q = lane >> 4;
    int ct0 = (wv & 1) * 2, rbase = (wv >> 1) * 2;

    floatx4 acc[2][10];
    conv_core(fin, wB, tile, acc, b, y0, tid, lane, wv, l15, q, ct0, rbase);

    __syncthreads();   // all waves done reading tile -> safe to overwrite with h

    // BN+SiLU -> h[pix 0..319][co] granule-major in the same LDS
    float sc4[2][4], sh4[2][4];
    #pragma unroll
    for (int c = 0; c < 2; ++c)
        #pragma unroll
        for (int r = 0; r < 4; ++r) {
            sc4[c][r] = scale[(ct0 + c) * 16 + q * 4 + r];
            sh4[c][r] = shift[(ct0 + c) * 16 + q * 4 + r];
        }
    #pragma unroll
    for (int pt = 0; pt < 10; ++pt) {
        const int r_o = rbase + pt / 5, c_o = (pt % 5) * 16;
        int pix = r_o * 80 + c_o + l15;     // block-local pixel 0..319
        #pragma unroll
        for (int c = 0; c < 2; ++c) {
            int gco = (ct0 + c) * 2 + (q >> 1);
            us4 v;
            #pragma unroll
            for (int r = 0; r < 4; ++r)
                v[r] = f2bf(silu_(acc[c][pt][r] * sc4[c][r] + sh4[c][r]));
            *(us4*)(tile + gco * CGS + pix * 8 + (q & 1) * 4) = v;
        }
    }

    // head B-frags: B[k=co][n] = reg_w[n][co] (n<4), obj_w[co] (n==4), else 0
    short8 hbf[2];
    #pragma unroll
    for (int kb2 = 0; kb2 < 2; ++kb2) {
        int k0 = kb2 * 32 + q * 8;
        short8 f = {};
        if (l15 < 4) {
            #pragma unroll
            for (int j = 0; j < 8; ++j) f[j] = (short)f2bf(reg_w[l15 * 64 + k0 + j]);
        } else if (l15 == 4) {
            #pragma unroll
            for (int j = 0; j < 8; ++j) f[j] = (short)f2bf(obj_w[k0 + j]);
        }
        hbf[kb2] = f;
    }

    __syncthreads();

    floatx4 zf = {0.0f, 0.0f, 0.0f, 0.0f};
    floatx4 acc5[5];
    #pragma unroll
    for (int t = 0; t < 5; ++t) acc5[t] = zf;
    #pragma unroll
    for (int t = 0; t < 5; ++t) {
        int mt = wv * 5 + t;
        #pragma unroll
        for (int kb2 = 0; kb2 < 2; ++kb2) {
            int pix = mt * 16 + l15;
            short8 a = *(const short8*)(tile + (kb2 * 4 + q) * CGS + pix * 8);
            acc5[t] = __builtin_amdgcn_mfma_f32_16x16x32_bf16(
                a, hbf[kb2], acc5[t], 0, 0, 0);
        }
    }

    float bias = 0.0f;
    if (l15 < 4) bias = reg_b[l15];
    else if (l15 == 4) bias = obj_b[0];

    #pragma unroll
    for (int t = 0; t < 5; ++t) {
        int mt = wv * 5 + t;
        #pragma unroll
        for (int r = 0; r < 4; ++r) {
            int pixL = mt * 16 + q * 4 + r;
            if (l15 < 5) {
                float v = acc5[t][r] + bias;
                float gx = (float)(pixL % 80);
                float gy = (float)(y0 + pixL / 80);
                float o;
                if (l15 == 0)      o = (v + gx) * 32.0f;
                else if (l15 == 1) o = (v + gy) * 32.0f;
                else if (l15 < 4)  o = __expf(v) * 32.0f;
                else               o = 1.0f / (1.0f + __expf(-v));
                out[((size_t)b * NPIX + y0 * 80 + pixL) * 5 + l15] = o;
            }
        }
    }
}

// ---------------------------------------------------------------------------
extern "C" void kernel_launch(void* const* d_in, const int* in_sizes, int n_in,
                              void* d_out, int out_size, void* d_ws, size_t ws_size,
                              hipStream_t stream) {
    const float* x          = (const float*)d_in[0];
    const float* stem_w     = (const float*)d_in[1];
    const float* stem_scale = (const float*)d_in[2];
    const float* stem_shift = (const float*)d_in[3];
    const float* c1_w       = (const float*)d_in[4];
    const float* c1_scale   = (const float*)d_in[5];
    const float* c1_shift   = (const float*)d_in[6];
    const float* c2_w       = (const float*)d_in[7];
    const float* c2_scale   = (const float*)d_in[8];
    const float* c2_shift   = (const float*)d_in[9];
    const float* reg_w      = (const float*)d_in[10];
    const float* reg_b      = (const float*)d_in[11];
    const float* obj_w      = (const float*)d_in[12];
    const float* obj_b      = (const float*)d_in[13];
    float* out = (float*)d_out;

    // ws (ushort units): wS[8192] | wB1[36864] | wB2[36864] | f1 | f2
    const size_t needed = ((size_t)8192 + 73728 + 2 * (size_t)64 * NPIX * 64) * 2;
    if (ws_size < needed) return;

    unsigned short* ws  = (unsigned short*)d_ws;
    unsigned short* wS  = ws;
    unsigned short* wB1 = ws + 8192;
    unsigned short* wB2 = wB1 + 36864;
    unsigned short* f1  = wB2 + 36864;
    unsigned short* f2  = f1 + (size_t)64 * NPIX * 64;

    rearr_w_kernel<<<320, 256, 0, stream>>>(stem_w, c1_w, c2_w, wS, wB1, wB2);
    stem_kernel<<<dim3(50, 64), 256, 0, stream>>>(x, wS, stem_scale, stem_shift, f1);
    conv3_kernel<<<dim3(20, 64), 256, 0, stream>>>(f1, wB1, c1_scale, c1_shift, f2);
    conv_head_kernel<<<dim3(20, 64), 256, 0, stream>>>(f2, wB2, c2_scale, c2_shift,
                                                       reg_w, reg_b, obj_w, obj_b, out);
}

// Round 6
// 445.887 us; speedup vs baseline: 1.8859x; 1.0100x over previous
//
#include <hip/hip_runtime.h>
#include <cstdint>

// SREChead: stem 1x1 (128->64) + 2x 3x3 (64->64), each BN+SiLU, then 1x1
// reg(4)/obj(1) heads + YOLOX decode. B=64, 80x80, stride 32.
// R6: conv = 4-ct N-blocking (1 LDS read : 4 MFMA) + ci-half-split staging
// (LDS 41KB -> 3 blocks/CU). Stem = fp32 row-staging [ci][129] (pure
// coalesced dwordx4 copy), bf16 transpose at fragment-build time.

typedef short short8 __attribute__((ext_vector_type(8)));
typedef float floatx4 __attribute__((ext_vector_type(4)));
typedef float fx4 __attribute__((ext_vector_type(4)));
typedef unsigned short us4 __attribute__((ext_vector_type(4)));

#define NPIX 6400
#define CGS  3952    // conv tile granule stride: 494 px * 8 us (6x82=492 used)
#define CGS2 2576    // h-tile granule stride: 322 px * 8 us (320 used)

static __device__ __forceinline__ unsigned short f2bf(float f) {
    unsigned u = __builtin_bit_cast(unsigned, f);
    u += 0x7fffu + ((u >> 16) & 1u);      // round-to-nearest-even
    return (unsigned short)(u >> 16);
}

static __device__ __forceinline__ float silu_(float v) {
    return v / (1.0f + __expf(-v));
}

// ---------------------------------------------------------------------------
// Rearrange weights to bf16 MFMA A-frag order.
//  wS  [kb(4)][ct(4)][lane][8]  from stem_w [64co][128ci]      (8192 el)
//  wB1 [kb(18)][ct(4)][lane][8] from c1_w [64co][64ci][3][3]   (36864 el)
//  wB2 same from c2_w
// co = ct*16+(lane&15); k = kb*32+(lane>>4)*8+j; conv: ci=k&63, tap=k>>6.
__global__ __launch_bounds__(256) void rearr_w_kernel(
    const float* __restrict__ ws_, const float* __restrict__ w1,
    const float* __restrict__ w2,
    unsigned short* __restrict__ wS, unsigned short* __restrict__ wB1,
    unsigned short* __restrict__ wB2) {
    int idx = blockIdx.x * 256 + threadIdx.x;          // 0..81919
    if (idx < 8192) {
        int e = idx;
        int j = e & 7, lane = (e >> 3) & 63, ct = (e >> 9) & 3, kb = e >> 11;
        int co = ct * 16 + (lane & 15);
        int ci = kb * 32 + ((lane >> 4) * 8) + j;
        wS[e] = f2bf(ws_[co * 128 + ci]);
        return;
    }
    idx -= 8192;
    const float* src = (idx < 36864) ? w1 : w2;
    unsigned short* dst = (idx < 36864) ? wB1 : wB2;
    int e = (idx < 36864) ? idx : idx - 36864;
    int j = e & 7, lane = (e >> 3) & 63, ct = (e >> 9) & 3, kb = e >> 11;
    int co = ct * 16 + (lane & 15);
    int k = kb * 32 + ((lane >> 4) * 8) + j;
    int ci = k & 63, tap = k >> 6;
    dst[e] = f2bf(src[(co * 64 + ci) * 9 + tap]);
}

// ---------------------------------------------------------------------------
// Stem: f1[b][p][co] = silu(bn(sum_ci x[b][ci][p] * W[co][ci]))  (NHWC bf16)
// Block: 128-px tile. Two phases of 64 ci: stage fp32 rows [64][129] (33 KB,
// padded -> conflict-free), frag-build transposes via 8x ds_read_b32 + pack.
__global__ __launch_bounds__(256) void stem_kernel(
    const float* __restrict__ x, const unsigned short* __restrict__ wS,
    const float* __restrict__ scale, const float* __restrict__ shift,
    unsigned short* __restrict__ f1) {
    __shared__ __align__(16) float xs[64 * 129];   // 33024 B
    int b = blockIdx.y;
    int tid = threadIdx.x;
    int pbase = blockIdx.x * 128;
    int lane = tid & 63, wv = tid >> 6;
    int l15 = lane & 15, q = lane >> 4;

    float sc[4][4], sh[4][4];
    #pragma unroll
    for (int ct = 0; ct < 4; ++ct)
        #pragma unroll
        for (int r = 0; r < 4; ++r) {
            sc[ct][r] = scale[ct * 16 + q * 4 + r];
            sh[ct][r] = shift[ct * 16 + q * 4 + r];
        }

    floatx4 acc[4][2];   // [ct][t]
    floatx4 zf = {0.0f, 0.0f, 0.0f, 0.0f};
    #pragma unroll
    for (int ct = 0; ct < 4; ++ct)
        #pragma unroll
        for (int t = 0; t < 2; ++t) acc[ct][t] = zf;

    #pragma unroll
    for (int p = 0; p < 2; ++p) {
        if (p) __syncthreads();        // WAR: phase-0 frag reads done
        // stage 64 ci rows x 128 px fp32: 2048 16B chunks, 8/thread, coalesced
        #pragma unroll
        for (int i = 0; i < 8; ++i) {
            int c = i * 256 + tid;
            int row = c >> 5, seg = c & 31;
            fx4 v = *(const fx4*)(
                x + ((size_t)(b * 128 + p * 64 + row)) * NPIX + pbase + seg * 4);
            *(fx4*)(xs + row * 129 + seg * 4) = v;
        }
        __syncthreads();

        #pragma unroll
        for (int kk = 0; kk < 2; ++kk) {
            int kb = p * 2 + kk;
            short8 wf[4];
            #pragma unroll
            for (int ct = 0; ct < 4; ++ct)
                wf[ct] = *(const short8*)(wS + ((kb * 4 + ct) * 64 + lane) * 8);
            short8 xf[2];
            #pragma unroll
            for (int t = 0; t < 2; ++t) {
                int px = (wv * 2 + t) * 16 + l15;
                const float* src = xs + (kk * 32 + q * 8) * 129 + px;
                unsigned short tmp[8];
                #pragma unroll
                for (int j = 0; j < 8; ++j) tmp[j] = f2bf(src[j * 129]);
                xf[t] = *(const short8*)tmp;
            }
            #pragma unroll
            for (int ct = 0; ct < 4; ++ct)
                #pragma unroll
                for (int t = 0; t < 2; ++t)
                    acc[ct][t] = __builtin_amdgcn_mfma_f32_16x16x32_bf16(
                        wf[ct], xf[t], acc[ct][t], 0, 0, 0);
        }
    }

    #pragma unroll
    for (int t = 0; t < 2; ++t) {
        int pg = pbase + (wv * 2 + t) * 16 + l15;
        unsigned short* dst = f1 + ((size_t)b * NPIX + pg) * 64;
        #pragma unroll
        for (int ct = 0; ct < 4; ++ct) {
            us4 v;
            #pragma unroll
            for (int r = 0; r < 4; ++r)
                v[r] = f2bf(silu_(acc[ct][t][r] * sc[ct][r] + sh[ct][r]));
            *(us4*)(dst + ct * 16 + q * 4) = v;
        }
    }
}

// ---------------------------------------------------------------------------
// Conv core, 4-ct N-blocking: wave wv owns output row y0+wv, all 64 co,
// 5 col-tiles. K split into 2 ci-halves; per half: stage 6x82x32ci tile
// (4 granules, 32 KB), then 9 taps. Each LDS B-read feeds 4 MFMAs.
static __device__ __forceinline__ void conv_core(
    const unsigned short* __restrict__ fin, const unsigned short* __restrict__ wB,
    unsigned short* tile, floatx4 (*acc)[5], int b, int y0,
    int tid, int lane, int wv, int l15, int q) {
    const unsigned short* fb = fin + (size_t)b * NPIX * 64;
    floatx4 zf = {0.0f, 0.0f, 0.0f, 0.0f};
    #pragma unroll
    for (int c4 = 0; c4 < 4; ++c4)
        #pragma unroll
        for (int pt = 0; pt < 5; ++pt) acc[c4][pt] = zf;

    #pragma unroll
    for (int half = 0; half < 2; ++half) {
        if (half) __syncthreads();     // WAR: half-0 reads done before restage
        #pragma unroll
        for (int i = 0; i < 8; ++i) {
            int cid = i * 256 + tid;   // 1968 = 492 pix * 4 granules
            if (cid < 1968) {
                int pixL = cid >> 2, g = cid & 3;
                int r = pixL / 82, c = pixL - r * 82;
                int gy = y0 - 1 + r, gx = c - 1;
                short8 v = {};
                if ((unsigned)gy < 80u && (unsigned)gx < 80u)
                    v = *(const short8*)(
                        fb + (size_t)(gy * 80 + gx) * 64 + half * 32 + g * 8);
                *(short8*)(tile + g * CGS + pixL * 8) = v;
            }
        }
        __syncthreads();

        #pragma unroll
        for (int trow = 0; trow < 3; ++trow) {
            const int dy = trow - 1;
            #pragma unroll
            for (int tc = 0; tc < 3; ++tc) {
                const int dx = tc - 1;
                const int kb = (trow * 3 + tc) * 2 + half;
                short8 w4[4];
                #pragma unroll
                for (int c4 = 0; c4 < 4; ++c4)
                    w4[c4] = *(const short8*)(wB + ((kb * 4 + c4) * 64 + lane) * 8);
                #pragma unroll
                for (int pt = 0; pt < 5; ++pt) {
                    int pix = (wv + 1 + dy) * 82 + pt * 16 + l15 + 1 + dx;
                    short8 b8 = *(const short8*)(tile + q * CGS + pix * 8);
                    #pragma unroll
                    for (int c4 = 0; c4 < 4; ++c4)
                        acc[c4][pt] = __builtin_amdgcn_mfma_f32_16x16x32_bf16(
                            w4[c4], b8, acc[c4][pt], 0, 0, 0);
                }
            }
        }
    }
}

// ---------------------------------------------------------------------------
__global__ __launch_bounds__(256, 3) void conv3_kernel(
    const unsigned short* __restrict__ fin, const unsigned short* __restrict__ wB,
    const float* __restrict__ scale, const float* __restrict__ shift,
    unsigned short* __restrict__ fout) {
    __shared__ __align__(16) unsigned short tile[8 * CGS2];  // 41216 B
    int b = blockIdx.y, y0 = blockIdx.x * 4;
    int tid = threadIdx.x;
    int lane = tid & 63, wv = tid >> 6;
    int l15 = lane & 15, q = lane >> 4;

    floatx4 acc[4][5];
    conv_core(fin, wB, tile, acc, b, y0, tid, lane, wv, l15, q);

    float sc4[4][4], sh4[4][4];
    #pragma unroll
    for (int c4 = 0; c4 < 4; ++c4)
        #pragma unroll
        for (int r = 0; r < 4; ++r) {
            sc4[c4][r] = scale[c4 * 16 + q * 4 + r];
            sh4[c4][r] = shift[c4 * 16 + q * 4 + r];
        }
    #pragma unroll
    for (int pt = 0; pt < 5; ++pt) {
        int pg = (y0 + wv) * 80 + pt * 16 + l15;
        unsigned short* dst = fout + ((size_t)b * NPIX + pg) * 64;
        #pragma unroll
        for (int c4 = 0; c4 < 4; ++c4) {
            us4 v;
            #pragma unroll
            for (int r = 0; r < 4; ++r)
                v[r] = f2bf(silu_(acc[c4][pt][r] * sc4[c4][r] + sh4[c4][r]));
            *(us4*)(dst + c4 * 16 + q * 4) = v;
        }
    }
}

// ---------------------------------------------------------------------------
__global__ __launch_bounds__(256, 3) void conv_head_kernel(
    const unsigned short* __restrict__ fin, const unsigned short* __restrict__ wB,
    const float* __restrict__ scale, const float* __restrict__ shift,
    const float* __restrict__ reg_w, const float* __restrict__ reg_b,
    const float* __restrict__ obj_w, const float* __restrict__ obj_b,
    float* __restrict__ out) {
    __shared__ __align__(16) unsigned short tile[8 * CGS2];  // 41216 B
    int b = blockIdx.y, y0 = blockIdx.x * 4;
    int tid = threadIdx.x;
    int lane = tid & 63, wv = tid >> 6;
    int l15 = lane & 15, q = lane >> 4;

    floatx4 acc[4][5];
    conv_core(fin, wB, tile, acc, b, y0, tid, lane, wv, l15, q);

    __syncthreads();   // conv reads done -> reuse LDS for h (granule stride CGS2)

    // BN+SiLU -> h[granule co>>3][pix 0..319] (stride CGS2, conflict-free)
    float sc4[4][4], sh4[4][4];
    #pragma unroll
    for (int c4 = 0; c4 < 4; ++c4)
        #pragma unroll
        for (int r = 0; r < 4; ++r) {
            sc4[c4][r] = scale[c4 * 16 + q * 4 + r];
            sh4[c4][r] = shift[c4 * 16 + q * 4 + r];
        }
    #pragma unroll
    for (int pt = 0; pt < 5; ++pt) {
        int pix = wv * 80 + pt * 16 + l15;   // block-local pixel 0..319
        #pragma unroll
        for (int c4 = 0; c4 < 4; ++c4) {
            int gco = c4 * 2 + (q >> 1);     // co>>3
            us4 v;
            #pragma unroll
            for (int r = 0; r < 4; ++r)
                v[r] = f2bf(silu_(acc[c4][pt][r] * sc4[c4][r] + sh4[c4][r]));
            *(us4*)(tile + gco * CGS2 + pix * 8 + (q & 1) * 4) = v;
        }
    }

    // head B-frags: B[k=co][n] = reg_w[n][co] (n<4), obj_w[co] (n==4), else 0
    short8 hbf[2];
    #pragma unroll
    for (int kb2 = 0; kb2 < 2; ++kb2) {
        int k0 = kb2 * 32 + q * 8;
        short8 f = {};
        if (l15 < 4) {
            #pragma unroll
            for (int j = 0; j < 8; ++j) f[j] = (short)f2bf(reg_w[l15 * 64 + k0 + j]);
        } else if (l15 == 4) {
            #pragma unroll
            for (int j = 0; j < 8; ++j) f[j] = (short)f2bf(obj_w[k0 + j]);
        }
        hbf[kb2] = f;
    }

    __syncthreads();

    floatx4 zf = {0.0f, 0.0f, 0.0f, 0.0f};
    floatx4 acc5[5];
    #pragma unroll
    for (int t = 0; t < 5; ++t) acc5[t] = zf;
    #pragma unroll
    for (int t = 0; t < 5; ++t) {
        int mt = wv * 5 + t;
        int pix = mt * 16 + l15;
        #pragma unroll
        for (int kb2 = 0; kb2 < 2; ++kb2) {
            short8 a = *(const short8*)(tile + (kb2 * 4 + q) * CGS2 + pix * 8);
            acc5[t] = __builtin_amdgcn_mfma_f32_16x16x32_bf16(
                a, hbf[kb2], acc5[t], 0, 0, 0);
        }
    }

    float bias = 0.0f;
    if (l15 < 4) bias = reg_b[l15];
    else if (l15 == 4) bias = obj_b[0];

    #pragma unroll
    for (int t = 0; t < 5; ++t) {
        int mt = wv * 5 + t;
        #pragma unroll
        for (int r = 0; r < 4; ++r) {
            int pixL = mt * 16 + q * 4 + r;
            if (l15 < 5) {
                float v = acc5[t][r] + bias;
                float gx = (float)(pixL % 80);
                float gy = (float)(y0 + pixL / 80);
                float o;
                if (l15 == 0)      o = (v + gx) * 32.0f;
                else if (l15 == 1) o = (v + gy) * 32.0f;
                else if (l15 < 4)  o = __expf(v) * 32.0f;
                else               o = 1.0f / (1.0f + __expf(-v));
                out[((size_t)b * NPIX + y0 * 80 + pixL) * 5 + l15] = o;
            }
        }
    }
}

// ---------------------------------------------------------------------------
extern "C" void kernel_launch(void* const* d_in, const int* in_sizes, int n_in,
                              void* d_out, int out_size, void* d_ws, size_t ws_size,
                              hipStream_t stream) {
    const float* x          = (const float*)d_in[0];
    const float* stem_w     = (const float*)d_in[1];
    const float* stem_scale = (const float*)d_in[2];
    const float* stem_shift = (const float*)d_in[3];
    const float* c1_w       = (const float*)d_in[4];
    const float* c1_scale   = (const float*)d_in[5];
    const float* c1_shift   = (const float*)d_in[6];
    const float* c2_w       = (const float*)d_in[7];
    const float* c2_scale   = (const float*)d_in[8];
    const float* c2_shift   = (const float*)d_in[9];
    const float* reg_w      = (const float*)d_in[10];
    const float* reg_b      = (const float*)d_in[11];
    const float* obj_w      = (const float*)d_in[12];
    const float* obj_b      = (const float*)d_in[13];
    float* out = (float*)d_out;

    // ws (ushort units): wS[8192] | wB1[36864] | wB2[36864] | f1 | f2
    const size_t needed = ((size_t)8192 + 73728 + 2 * (size_t)64 * NPIX * 64) * 2;
    if (ws_size < needed) return;

    unsigned short* ws  = (unsigned short*)d_ws;
    unsigned short* wS  = ws;
    unsigned short* wB1 = ws + 8192;
    unsigned short* wB2 = wB1 + 36864;
    unsigned short* f1  = wB2 + 36864;
    unsigned short* f2  = f1 + (size_t)64 * NPIX * 64;

    rearr_w_kernel<<<320, 256, 0, stream>>>(stem_w, c1_w, c2_w, wS, wB1, wB2);
    stem_kernel<<<dim3(50, 64), 256, 0, stream>>>(x, wS, stem_scale, stem_shift, f1);
    conv3_kernel<<<dim3(20, 64), 256, 0, stream>>>(f1, wB1, c1_scale, c1_shift, f2);
    conv_head_kernel<<<dim3(20, 64), 256, 0, stream>>>(f2, wB2, c2_scale, c2_shift,
                                                       reg_w, reg_b, obj_w, obj_b, out);
}